// Round 1
// baseline (587.756 us; speedup 1.0000x reference)
//
#include <hip/hip_runtime.h>
#include <stdint.h>

#define Bb 32
#define Ss 1024
#define Dd 1024

typedef __attribute__((ext_vector_type(8))) short short8v;
typedef __attribute__((ext_vector_type(4))) float f32x4;

struct __align__(16) F4 { float v[4]; };

typedef __attribute__((address_space(1))) const void gvoid;
typedef __attribute__((address_space(3))) void svoid;

__device__ inline void gl_lds16(void* lds, const void* g) {
  __builtin_amdgcn_global_load_lds((gvoid*)g, (svoid*)lds, 16, 0, 0);
}

__device__ inline float wredmax(float v) {
#pragma unroll
  for (int o = 32; o > 0; o >>= 1) v = fmaxf(v, __shfl_xor(v, o));
  return v;
}
__device__ inline float wredsum(float v) {
#pragma unroll
  for (int o = 32; o > 0; o >>= 1) v += __shfl_xor(v, o);
  return v;
}

// round-to-nearest-even f32 -> bf16 bits (inputs are finite normals)
__device__ inline unsigned short f2bf(float f) {
  uint32_t x = __float_as_uint(f);
  uint32_t r = (x + 0x7fffu + ((x >> 16) & 1u)) >> 16;
  return (unsigned short)r;
}

// ---------------- K1: special-token masks + 1/len + zero the accumulator ----
__global__ __launch_bounds__(256) void k_mask(const int* __restrict__ idsS,
                                              const int* __restrict__ idsT,
                                              float* extS, float* extT,
                                              float* invLenS, float* invLenT,
                                              float* wsAcc) {
  const int b = blockIdx.x, tid = threadIdx.x;
  if (b == 0 && tid == 0) wsAcc[0] = 0.0f;
  __shared__ float sh[4];
  for (int side = 0; side < 2; ++side) {
    const int* ids = side ? idsT : idsS;
    float* ext = side ? extT : extS;
    float* il = side ? invLenT : invLenS;
    int cnt = 0;
    for (int i = tid; i < Ss; i += 256) {
      int v = ids[b * Ss + i];
      bool sp = (v == 0) || (v == 101) || (v == 102);
      ext[b * Ss + i] = sp ? -10000.0f : 0.0f;
      cnt += sp ? 0 : 1;
    }
    float c = wredsum((float)cnt);
    if ((tid & 63) == 0) sh[tid >> 6] = c;
    __syncthreads();
    if (tid == 0) il[b] = 1.0f / (sh[0] + sh[1] + sh[2] + sh[3]);
    __syncthreads();
  }
}

// ---------------- K2: f32 -> bf16 convert (both hidden tensors) -------------
__global__ __launch_bounds__(256) void k_cvt(const float* __restrict__ src,
                                             const float* __restrict__ tgt,
                                             unsigned short* __restrict__ srcB,
                                             unsigned short* __restrict__ tgtB) {
  const size_t n = (size_t)Bb * Ss * Dd;
  const size_t units = (2 * n) / 4;
  const size_t stride = (size_t)gridDim.x * blockDim.x;
  for (size_t u = (size_t)blockIdx.x * blockDim.x + threadIdx.x; u < units; u += stride) {
    size_t e = u * 4;
    const float* ip;
    unsigned short* op;
    if (e < n) { ip = src + e; op = srcB + e; }
    else       { ip = tgt + (e - n); op = tgtB + (e - n); }
    F4 x = *(const F4*)ip;
    ushort4 o;
    o.x = f2bf(x.v[0]); o.y = f2bf(x.v[1]); o.z = f2bf(x.v[2]); o.w = f2bf(x.v[3]);
    *(ushort4*)op = o;
  }
}

// ---------------- K3: batched bf16 MFMA GEMM, scores = src @ tgt^T ----------
// m97-style: 128x128 tile, BK=32, 4 waves (2x2), global_load_lds width=16.
__global__ __launch_bounds__(256) void k_gemm(const unsigned short* __restrict__ Ag0,
                                              const unsigned short* __restrict__ Bg0,
                                              float* __restrict__ C) {
  __shared__ __align__(16) unsigned short As[128 * 32];
  __shared__ __align__(16) unsigned short Bs[128 * 32];
  const int tile = blockIdx.x, b = blockIdx.y;
  const int tm = tile >> 3, tn = tile & 7;
  const int tid = threadIdx.x, w = tid >> 6, l = tid & 63;
  const int wr = w >> 1, wc = w & 1;
  const int lr = l & 15, lk = (l >> 4) * 8;
  const size_t bb = (size_t)b * (Ss * Dd);
  const unsigned short* Ag = Ag0 + bb + (size_t)(tm * 128) * Dd;
  const unsigned short* Bg = Bg0 + bb + (size_t)(tn * 128) * Dd;
  const int rA = l >> 2, kq = (l & 3) * 8;

  f32x4 acc[4][4];
#pragma unroll
  for (int m = 0; m < 4; ++m)
#pragma unroll
    for (int n = 0; n < 4; ++n) acc[m][n] = (f32x4){0.f, 0.f, 0.f, 0.f};

  for (int kt = 0; kt < Dd / 32; ++kt) {
    const int kb = kt * 32;
    __syncthreads();  // previous tile's ds_reads complete before overwrite
#pragma unroll
    for (int i = 0; i < 2; ++i) {
      const int c = w * 2 + i;  // wave-uniform chunk id, 8 chunks cover the tile
      gl_lds16((char*)As + c * 1024, Ag + (size_t)(c * 16 + rA) * Dd + kb + kq);
      gl_lds16((char*)Bs + c * 1024, Bg + (size_t)(c * 16 + rA) * Dd + kb + kq);
    }
    __syncthreads();  // compiler drains vmcnt here; tile ready
    short8v af[4], bf[4];
#pragma unroll
    for (int m = 0; m < 4; ++m)
      af[m] = *(const short8v*)&As[(wr * 64 + m * 16 + lr) * 32 + lk];
#pragma unroll
    for (int n = 0; n < 4; ++n)
      bf[n] = *(const short8v*)&Bs[(wc * 64 + n * 16 + lr) * 32 + lk];
#pragma unroll
    for (int m = 0; m < 4; ++m)
#pragma unroll
      for (int n = 0; n < 4; ++n)
        acc[m][n] = __builtin_amdgcn_mfma_f32_16x16x32_bf16(af[m], bf[n], acc[m][n], 0, 0, 0);
  }

  // C/D layout: col = lane&15, row = (lane>>4)*4 + j  [m89-verified]
  float* Cb = C + (size_t)b * (Ss * Ss);
  const int r0 = tm * 128 + wr * 64 + (l >> 4) * 4;
  const int c0 = tn * 128 + wc * 64 + lr;
#pragma unroll
  for (int m = 0; m < 4; ++m)
#pragma unroll
    for (int n = 0; n < 4; ++n)
#pragma unroll
      for (int j = 0; j < 4; ++j)
        Cb[(size_t)(r0 + m * 16 + j) * Ss + c0 + n * 16] = acc[m][n][j];
}

// ---------------- K4: row stats (max, 1/sum) + partial col stats ------------
// grid (32 s-chunks, B). Wave-per-row for row softmax; each lane owns 16
// fixed columns for the online col softmax partials (partial id = sc*4+w).
__global__ __launch_bounds__(256) void k_stats(const float* __restrict__ scores,
                                               const float* __restrict__ extS,
                                               const float* __restrict__ extT,
                                               float* __restrict__ rowM,
                                               float* __restrict__ rowIS,
                                               float* __restrict__ pcM,
                                               float* __restrict__ pcS) {
  const int sc = blockIdx.x, b = blockIdx.y;
  const int tid = threadIdx.x, w = tid >> 6, l = tid & 63;
  F4 et[4];
  const float* etp = extT + b * Ss;
#pragma unroll
  for (int c = 0; c < 4; ++c) et[c] = *(const F4*)&etp[c * 256 + l * 4];
  float cm[16], cs[16];
#pragma unroll
  for (int i = 0; i < 16; ++i) { cm[i] = -INFINITY; cs[i] = 0.0f; }
  const float* esp = extS + b * Ss;
  const size_t bbase = (size_t)b * (Ss * Ss);

  for (int it = 0; it < 8; ++it) {
    const int s = sc * 32 + it * 4 + w;
    const float* rp = scores + bbase + (size_t)s * Ss;
    F4 x[4];
#pragma unroll
    for (int c = 0; c < 4; ++c) x[c] = *(const F4*)&rp[c * 256 + l * 4];
    const float es = esp[s];
    float rm = -INFINITY;
#pragma unroll
    for (int c = 0; c < 4; ++c)
#pragma unroll
      for (int j = 0; j < 4; ++j) rm = fmaxf(rm, x[c].v[j] + et[c].v[j]);
    rm = wredmax(rm);
    float rs = 0.0f;
#pragma unroll
    for (int c = 0; c < 4; ++c)
#pragma unroll
      for (int j = 0; j < 4; ++j) rs += __expf(x[c].v[j] + et[c].v[j] - rm);
    rs = wredsum(rs);
    if (l == 0) { rowM[b * Ss + s] = rm; rowIS[b * Ss + s] = 1.0f / rs; }
    // online col update (cols this lane owns are fixed across rows)
#pragma unroll
    for (int c = 0; c < 4; ++c)
#pragma unroll
      for (int j = 0; j < 4; ++j) {
        const int i = c * 4 + j;
        const float y = x[c].v[j] + es;
        const float ym = fmaxf(cm[i], y);
        cs[i] = cs[i] * __expf(cm[i] - ym) + __expf(y - ym);
        cm[i] = ym;
      }
  }
  const int p = sc * 4 + w;
  float* pm = pcM + ((size_t)b * 128 + p) * Ss;
  float* ps = pcS + ((size_t)b * 128 + p) * Ss;
#pragma unroll
  for (int c = 0; c < 4; ++c) {
    F4 om, os;
#pragma unroll
    for (int j = 0; j < 4; ++j) { om.v[j] = cm[c * 4 + j]; os.v[j] = cs[c * 4 + j]; }
    *(F4*)&pm[c * 256 + l * 4] = om;
    *(F4*)&ps[c * 256 + l * 4] = os;
  }
}

// ---------------- K5: merge 128 col partials -> colmax, 1/colsum ------------
__global__ __launch_bounds__(256) void k_merge(const float* __restrict__ pcM,
                                               const float* __restrict__ pcS,
                                               float* __restrict__ colM,
                                               float* __restrict__ colIS) {
  const int i = blockIdx.x * 256 + threadIdx.x;  // 0..B*S-1
  const int b = i >> 10, t = i & 1023;
  const float* pm = pcM + (size_t)b * 128 * Ss + t;
  const float* ps = pcS + (size_t)b * 128 * Ss + t;
  float M = -INFINITY, Sm = 0.0f;
  for (int p = 0; p < 128; ++p) {
    const float m2 = pm[(size_t)p * Ss];
    const float s2 = ps[(size_t)p * Ss];
    const float nm = fmaxf(M, m2);
    Sm = Sm * __expf(M - nm) + s2 * __expf(m2 - nm);
    M = nm;
  }
  colM[i] = M;
  colIS[i] = 1.0f / Sm;
}

// ---------------- K6: guide-weighted prob sums (both directions) ------------
__global__ __launch_bounds__(256) void k_wsum(const float* __restrict__ scores,
                                              const float* __restrict__ guide,
                                              const float* __restrict__ rowM,
                                              const float* __restrict__ rowIS,
                                              const float* __restrict__ colM,
                                              const float* __restrict__ colIS,
                                              const float* __restrict__ extS,
                                              const float* __restrict__ extT,
                                              const float* __restrict__ invLenS,
                                              const float* __restrict__ invLenT,
                                              float* __restrict__ wsAcc) {
  const size_t units = (size_t)Bb * Ss * (Ss / 4);
  const size_t stride = (size_t)gridDim.x * blockDim.x;
  float acc = 0.0f;
  for (size_t u = (size_t)blockIdx.x * blockDim.x + threadIdx.x; u < units; u += stride) {
    const int tq = (int)(u & 255);
    const int s = (int)((u >> 8) & 1023);
    const int b = (int)(u >> 18);
    const size_t ro = ((size_t)b * Ss + s) * Ss + tq * 4;
    F4 sc4 = *(const F4*)(scores + ro);
    F4 g4 = *(const F4*)(guide + ro);
    const int bs = b * Ss + s;
    const float rm = rowM[bs], irs = rowIS[bs], es = extS[bs];
    const float ils = invLenS[b], ilt = invLenT[b];
    const int bt = b * Ss + tq * 4;
    F4 et4 = *(const F4*)(extT + bt);
    F4 cm4 = *(const F4*)(colM + bt);
    F4 ic4 = *(const F4*)(colIS + bt);
#pragma unroll
    for (int j = 0; j < 4; ++j) {
      const float psrc = __expf(sc4.v[j] + et4.v[j] - rm) * irs * ils;
      const float ptgt = __expf(sc4.v[j] + es - cm4.v[j]) * ic4.v[j] * ilt;
      acc += (psrc + ptgt) * g4.v[j];
    }
  }
  acc = wredsum(acc);
  __shared__ float sh[4];
  if ((threadIdx.x & 63) == 0) sh[threadIdx.x >> 6] = acc;
  __syncthreads();
  if (threadIdx.x == 0) atomicAdd(wsAcc, sh[0] + sh[1] + sh[2] + sh[3]);
}

// ---------------- K7: finalize --------------------------------------------
__global__ void k_final(const float* __restrict__ wsAcc, float* __restrict__ out) {
  out[0] = -wsAcc[0] / (float)Bb;
}

extern "C" void kernel_launch(void* const* d_in, const int* in_sizes, int n_in,
                              void* d_out, int out_size, void* d_ws, size_t ws_size,
                              hipStream_t stream) {
  const float* hsrc = (const float*)d_in[0];
  const float* htgt = (const float*)d_in[1];
  const int* isrc = (const int*)d_in[2];
  const int* itgt = (const int*)d_in[3];
  const float* guide = (const float*)d_in[4];
  float* out = (float*)d_out;

  const size_t n = (size_t)Bb * Ss * Dd;  // 33554432
  char* w = (char*)d_ws;
  size_t off = 0;
  auto alloc = [&](size_t bytes) -> void* {
    void* p = (void*)(w + off);
    off += (bytes + 255) & ~(size_t)255;
    return p;
  };
  unsigned short* srcB = (unsigned short*)alloc(n * 2);          // 64 MB
  unsigned short* tgtB = (unsigned short*)alloc(n * 2);          // 64 MB
  float* scores = (float*)alloc((size_t)Bb * Ss * Ss * 4);       // 128 MB
  float* extS  = (float*)alloc((size_t)Bb * Ss * 4);
  float* extT  = (float*)alloc((size_t)Bb * Ss * 4);
  float* rowM  = (float*)alloc((size_t)Bb * Ss * 4);
  float* rowIS = (float*)alloc((size_t)Bb * Ss * 4);
  float* colM  = (float*)alloc((size_t)Bb * Ss * 4);
  float* colIS = (float*)alloc((size_t)Bb * Ss * 4);
  float* invLenS = (float*)alloc(Bb * 4);
  float* invLenT = (float*)alloc(Bb * 4);
  float* wsAcc = (float*)alloc(256);
  float* pcM = (float*)alloc((size_t)Bb * 128 * Ss * 4);         // 16 MB
  float* pcS = (float*)alloc((size_t)Bb * 128 * Ss * 4);         // 16 MB

  k_mask<<<Bb, 256, 0, stream>>>(isrc, itgt, extS, extT, invLenS, invLenT, wsAcc);
  k_cvt<<<4096, 256, 0, stream>>>(hsrc, htgt, srcB, tgtB);
  k_gemm<<<dim3(64, Bb), 256, 0, stream>>>(srcB, tgtB, scores);
  k_stats<<<dim3(32, Bb), 256, 0, stream>>>(scores, extS, extT, rowM, rowIS, pcM, pcS);
  k_merge<<<128, 256, 0, stream>>>(pcM, pcS, colM, colIS);
  k_wsum<<<2048, 256, 0, stream>>>(scores, guide, rowM, rowIS, colM, colIS,
                                   extS, extT, invLenS, invLenT, wsAcc);
  k_final<<<1, 1, 0, stream>>>(wsAcc, out);
}

// Round 2
// 550.645 us; speedup vs baseline: 1.0674x; 1.0674x over previous
//
#include <hip/hip_runtime.h>
#include <stdint.h>

#define Bb 32
#define Ss 1024
#define Dd 1024

typedef __attribute__((ext_vector_type(8))) short short8v;
typedef __attribute__((ext_vector_type(4))) float f32x4;

struct __align__(16) F4 { float v[4]; };

typedef __attribute__((address_space(1))) const void gvoid;
typedef __attribute__((address_space(3))) void svoid;

__device__ inline void gl_lds16(void* lds, const void* g) {
  __builtin_amdgcn_global_load_lds((gvoid*)g, (svoid*)lds, 16, 0, 0);
}

__device__ inline float wredmax(float v) {
#pragma unroll
  for (int o = 32; o > 0; o >>= 1) v = fmaxf(v, __shfl_xor(v, o));
  return v;
}
__device__ inline float wredsum(float v) {
#pragma unroll
  for (int o = 32; o > 0; o >>= 1) v += __shfl_xor(v, o);
  return v;
}

// round-to-nearest-even f32 -> bf16 bits (inputs are finite normals)
__device__ inline unsigned short f2bf(float f) {
  uint32_t x = __float_as_uint(f);
  uint32_t r = (x + 0x7fffu + ((x >> 16) & 1u)) >> 16;
  return (unsigned short)r;
}

// ---------------- K1: special-token masks + 1/len + zero the accumulator ----
__global__ __launch_bounds__(256) void k_mask(const int* __restrict__ idsS,
                                              const int* __restrict__ idsT,
                                              float* extS, float* extT,
                                              float* invLenS, float* invLenT,
                                              float* wsAcc) {
  const int b = blockIdx.x, tid = threadIdx.x;
  if (b == 0 && tid == 0) wsAcc[0] = 0.0f;
  __shared__ float sh[4];
  for (int side = 0; side < 2; ++side) {
    const int* ids = side ? idsT : idsS;
    float* ext = side ? extT : extS;
    float* il = side ? invLenT : invLenS;
    int cnt = 0;
    for (int i = tid; i < Ss; i += 256) {
      int v = ids[b * Ss + i];
      bool sp = (v == 0) || (v == 101) || (v == 102);
      ext[b * Ss + i] = sp ? -10000.0f : 0.0f;
      cnt += sp ? 0 : 1;
    }
    float c = wredsum((float)cnt);
    if ((tid & 63) == 0) sh[tid >> 6] = c;
    __syncthreads();
    if (tid == 0) il[b] = 1.0f / (sh[0] + sh[1] + sh[2] + sh[3]);
    __syncthreads();
  }
}

// ---------------- K2: f32 -> bf16 convert, 8 elems/lane ---------------------
__global__ __launch_bounds__(256) void k_cvt(const float* __restrict__ src,
                                             const float* __restrict__ tgt,
                                             unsigned short* __restrict__ srcB,
                                             unsigned short* __restrict__ tgtB) {
  const size_t n = (size_t)Bb * Ss * Dd;
  const size_t units = (2 * n) / 8;
  const size_t stride = (size_t)gridDim.x * blockDim.x;
  for (size_t u = (size_t)blockIdx.x * blockDim.x + threadIdx.x; u < units; u += stride) {
    size_t e = u * 8;
    const float* ip;
    unsigned short* op;
    if (e < n) { ip = src + e; op = srcB + e; }
    else       { ip = tgt + (e - n); op = tgtB + (e - n); }
    F4 x0 = *(const F4*)ip;
    F4 x1 = *(const F4*)(ip + 4);
    union { unsigned short u16[8]; short8v v; } o;
#pragma unroll
    for (int j = 0; j < 4; ++j) {
      o.u16[j] = f2bf(x0.v[j]);
      o.u16[4 + j] = f2bf(x1.v[j]);
    }
    *(short8v*)op = o.v;
  }
}

// ---------------- K3: batched bf16 MFMA GEMM, scores = src @ tgt^T ----------
// 128x128 tile, BK=64, 4 waves (2x2). XOR-swizzled LDS (pre-swizzled global
// source + swizzled ds_read, rule #21) -> conflict-free per 16-lane phase.
// Swapped-operand MFMA so each lane holds 4 consecutive tgt-cols -> f32x4 C.
__global__ __launch_bounds__(256) void k_gemm(const unsigned short* __restrict__ Ag0,
                                              const unsigned short* __restrict__ Bg0,
                                              float* __restrict__ C) {
  __shared__ __align__(16) unsigned short As[128 * 64];  // 16 KB
  __shared__ __align__(16) unsigned short Bs[128 * 64];  // 16 KB
  const int tile = blockIdx.x, b = blockIdx.y;
  const int tm = tile >> 3, tn = tile & 7;
  const int tid = threadIdx.x, w = tid >> 6, l = tid & 63;
  const int wr = w >> 1, wc = w & 1;
  const int lr = l & 15;
  const size_t bb = (size_t)b * (Ss * Dd);
  const unsigned short* Ag = Ag0 + bb + (size_t)(tm * 128) * Dd;
  const unsigned short* Bg = Bg0 + bb + (size_t)(tn * 128) * Dd;
  // staging: chunk c covers rows c*8..c*8+7 (row = 128B); lane l -> LDS byte
  // c*1024 + l*16 = (row c*8+(l>>3), slot l&7). Source kslot = (l&7)^(l>>3)
  // so that read-side slot = ks ^ (row&7) finds its data.
  const int srow = l >> 3;
  const int skslot = (l & 7) ^ srow;

  f32x4 acc[4][4];
#pragma unroll
  for (int m = 0; m < 4; ++m)
#pragma unroll
    for (int n = 0; n < 4; ++n) acc[m][n] = (f32x4){0.f, 0.f, 0.f, 0.f};

  for (int kt = 0; kt < Dd / 64; ++kt) {
    const int kb = kt * 64;
    __syncthreads();  // previous step's ds_reads complete before overwrite
#pragma unroll
    for (int i = 0; i < 4; ++i) {
      const int c = w * 4 + i;  // wave-uniform chunk id, 16 chunks per array
      gl_lds16((char*)As + c * 1024, Ag + (size_t)(c * 8 + srow) * Dd + kb + skslot * 8);
      gl_lds16((char*)Bs + c * 1024, Bg + (size_t)(c * 8 + srow) * Dd + kb + skslot * 8);
    }
    __syncthreads();  // compiler drains vmcnt here; tile ready
#pragma unroll
    for (int kk = 0; kk < 2; ++kk) {
      const int ks = kk * 4 + (l >> 4);  // kslot 0..7 (16B units of the k-dim)
      short8v af[4], bf[4];
#pragma unroll
      for (int m = 0; m < 4; ++m) {
        const int row = wr * 64 + m * 16 + lr;
        af[m] = *(const short8v*)&As[row * 64 + ((ks ^ (row & 7)) * 8)];
      }
#pragma unroll
      for (int n = 0; n < 4; ++n) {
        const int row = wc * 64 + n * 16 + lr;
        bf[n] = *(const short8v*)&Bs[row * 64 + ((ks ^ (row & 7)) * 8)];
      }
#pragma unroll
      for (int m = 0; m < 4; ++m)
#pragma unroll
        for (int n = 0; n < 4; ++n)
          acc[m][n] = __builtin_amdgcn_mfma_f32_16x16x32_bf16(bf[n], af[m], acc[m][n], 0, 0, 0);
    }
  }

  // swapped operands: D-row (reg dim) = tgt, D-col (lane&15) = src.
  // lane holds C[src = base_m + lr][tgt = base_n + (l>>4)*4 + j], j=0..3 -> f32x4
  float* Cb = C + (size_t)b * (Ss * Ss);
  const int sr0 = tm * 128 + wr * 64 + lr;
  const int tc0 = tn * 128 + wc * 64 + (l >> 4) * 4;
#pragma unroll
  for (int m = 0; m < 4; ++m)
#pragma unroll
    for (int n = 0; n < 4; ++n)
      *(f32x4*)&Cb[(size_t)(sr0 + m * 16) * Ss + tc0 + n * 16] = acc[m][n];
}

// ---------------- K4: row stats (max, 1/sum) + partial col stats ------------
// grid (32 s-chunks, B). Wave-per-row for row softmax; each lane owns 16
// fixed columns for the online col partials; cross-wave merge in LDS so each
// block emits ONE partial (32 total per column).
__global__ __launch_bounds__(256) void k_stats(const float* __restrict__ scores,
                                               const float* __restrict__ extS,
                                               const float* __restrict__ extT,
                                               float* __restrict__ rowM,
                                               float* __restrict__ rowIS,
                                               float* __restrict__ pcM,
                                               float* __restrict__ pcS) {
  const int sc = blockIdx.x, b = blockIdx.y;
  const int tid = threadIdx.x, w = tid >> 6, l = tid & 63;
  __shared__ float smM[3][1024], smS[3][1024];  // 24 KB
  F4 et[4];
  const float* etp = extT + b * Ss;
#pragma unroll
  for (int c = 0; c < 4; ++c) et[c] = *(const F4*)&etp[c * 256 + l * 4];
  float cm[16], cs[16];
#pragma unroll
  for (int i = 0; i < 16; ++i) { cm[i] = -INFINITY; cs[i] = 0.0f; }
  const float* esp = extS + b * Ss;
  const size_t bbase = (size_t)b * (Ss * Ss);

  for (int it = 0; it < 8; ++it) {
    const int s = sc * 32 + it * 4 + w;
    const float* rp = scores + bbase + (size_t)s * Ss;
    F4 x[4];
#pragma unroll
    for (int c = 0; c < 4; ++c) x[c] = *(const F4*)&rp[c * 256 + l * 4];
    const float es = esp[s];
    float rm = -INFINITY;
#pragma unroll
    for (int c = 0; c < 4; ++c)
#pragma unroll
      for (int j = 0; j < 4; ++j) rm = fmaxf(rm, x[c].v[j] + et[c].v[j]);
    rm = wredmax(rm);
    float rs = 0.0f;
#pragma unroll
    for (int c = 0; c < 4; ++c)
#pragma unroll
      for (int j = 0; j < 4; ++j) rs += __expf(x[c].v[j] + et[c].v[j] - rm);
    rs = wredsum(rs);
    if (l == 0) { rowM[b * Ss + s] = rm; rowIS[b * Ss + s] = 1.0f / rs; }
#pragma unroll
    for (int c = 0; c < 4; ++c)
#pragma unroll
      for (int j = 0; j < 4; ++j) {
        const int i = c * 4 + j;
        const float y = x[c].v[j] + es;
        const float ym = fmaxf(cm[i], y);
        cs[i] = cs[i] * __expf(cm[i] - ym) + __expf(y - ym);
        cm[i] = ym;
      }
  }
  // cross-wave merge: waves 1-3 park partials in LDS, wave 0 folds them in
  if (w > 0) {
#pragma unroll
    for (int c = 0; c < 4; ++c) {
      F4 om, os;
#pragma unroll
      for (int j = 0; j < 4; ++j) { om.v[j] = cm[c * 4 + j]; os.v[j] = cs[c * 4 + j]; }
      *(F4*)&smM[w - 1][c * 256 + l * 4] = om;
      *(F4*)&smS[w - 1][c * 256 + l * 4] = os;
    }
  }
  __syncthreads();
  if (w == 0) {
    float* pm = pcM + ((size_t)b * 32 + sc) * Ss;
    float* ps = pcS + ((size_t)b * 32 + sc) * Ss;
#pragma unroll
    for (int c = 0; c < 4; ++c) {
      F4 om, os;
#pragma unroll
      for (int j = 0; j < 4; ++j) {
        const int i = c * 4 + j;
        const int col = c * 256 + l * 4 + j;
        float M = cm[i], Sm = cs[i];
#pragma unroll
        for (int q = 0; q < 3; ++q) {
          const float m2 = smM[q][col], s2 = smS[q][col];
          const float nm = fmaxf(M, m2);
          Sm = Sm * __expf(M - nm) + s2 * __expf(m2 - nm);
          M = nm;
        }
        om.v[j] = M; os.v[j] = Sm;
      }
      *(F4*)&pm[c * 256 + l * 4] = om;
      *(F4*)&ps[c * 256 + l * 4] = os;
    }
  }
}

// ---------------- K5: merge 32 col partials -> colmax, 1/colsum -------------
__global__ __launch_bounds__(256) void k_merge(const float* __restrict__ pcM,
                                               const float* __restrict__ pcS,
                                               float* __restrict__ colM,
                                               float* __restrict__ colIS) {
  const int i = blockIdx.x * 256 + threadIdx.x;  // 0..B*S-1
  const int b = i >> 10, t = i & 1023;
  const float* pm = pcM + (size_t)b * 32 * Ss + t;
  const float* ps = pcS + (size_t)b * 32 * Ss + t;
  float M = -INFINITY, Sm = 0.0f;
#pragma unroll 4
  for (int p = 0; p < 32; ++p) {
    const float m2 = pm[(size_t)p * Ss];
    const float s2 = ps[(size_t)p * Ss];
    const float nm = fmaxf(M, m2);
    Sm = Sm * __expf(M - nm) + s2 * __expf(m2 - nm);
    M = nm;
  }
  colM[i] = M;
  colIS[i] = 1.0f / Sm;
}

// ---------------- K6: guide-weighted prob sums (both directions) ------------
__global__ __launch_bounds__(256) void k_wsum(const float* __restrict__ scores,
                                              const float* __restrict__ guide,
                                              const float* __restrict__ rowM,
                                              const float* __restrict__ rowIS,
                                              const float* __restrict__ colM,
                                              const float* __restrict__ colIS,
                                              const float* __restrict__ extS,
                                              const float* __restrict__ extT,
                                              const float* __restrict__ invLenS,
                                              const float* __restrict__ invLenT,
                                              float* __restrict__ wsAcc) {
  const size_t units = (size_t)Bb * Ss * (Ss / 4);
  const size_t stride = (size_t)gridDim.x * blockDim.x;
  float acc = 0.0f;
  for (size_t u = (size_t)blockIdx.x * blockDim.x + threadIdx.x; u < units; u += stride) {
    const int tq = (int)(u & 255);
    const int s = (int)((u >> 8) & 1023);
    const int b = (int)(u >> 18);
    const size_t ro = ((size_t)b * Ss + s) * Ss + tq * 4;
    F4 sc4 = *(const F4*)(scores + ro);
    F4 g4 = *(const F4*)(guide + ro);
    const int bs = b * Ss + s;
    const float rm = rowM[bs], irs = rowIS[bs], es = extS[bs];
    const float ils = invLenS[b], ilt = invLenT[b];
    const int bt = b * Ss + tq * 4;
    F4 et4 = *(const F4*)(extT + bt);
    F4 cm4 = *(const F4*)(colM + bt);
    F4 ic4 = *(const F4*)(colIS + bt);
#pragma unroll
    for (int j = 0; j < 4; ++j) {
      const float psrc = __expf(sc4.v[j] + et4.v[j] - rm) * irs * ils;
      const float ptgt = __expf(sc4.v[j] + es - cm4.v[j]) * ic4.v[j] * ilt;
      acc += (psrc + ptgt) * g4.v[j];
    }
  }
  acc = wredsum(acc);
  __shared__ float sh[4];
  if ((threadIdx.x & 63) == 0) sh[threadIdx.x >> 6] = acc;
  __syncthreads();
  if (threadIdx.x == 0) atomicAdd(wsAcc, sh[0] + sh[1] + sh[2] + sh[3]);
}

// ---------------- K7: finalize --------------------------------------------
__global__ void k_final(const float* __restrict__ wsAcc, float* __restrict__ out) {
  out[0] = -wsAcc[0] / (float)Bb;
}

extern "C" void kernel_launch(void* const* d_in, const int* in_sizes, int n_in,
                              void* d_out, int out_size, void* d_ws, size_t ws_size,
                              hipStream_t stream) {
  const float* hsrc = (const float*)d_in[0];
  const float* htgt = (const float*)d_in[1];
  const int* isrc = (const int*)d_in[2];
  const int* itgt = (const int*)d_in[3];
  const float* guide = (const float*)d_in[4];
  float* out = (float*)d_out;

  const size_t n = (size_t)Bb * Ss * Dd;  // 33554432
  char* w = (char*)d_ws;
  size_t off = 0;
  auto alloc = [&](size_t bytes) -> void* {
    void* p = (void*)(w + off);
    off += (bytes + 255) & ~(size_t)255;
    return p;
  };
  unsigned short* srcB = (unsigned short*)alloc(n * 2);          // 64 MB
  unsigned short* tgtB = (unsigned short*)alloc(n * 2);          // 64 MB
  float* scores = (float*)alloc((size_t)Bb * Ss * Ss * 4);       // 128 MB
  float* extS  = (float*)alloc((size_t)Bb * Ss * 4);
  float* extT  = (float*)alloc((size_t)Bb * Ss * 4);
  float* rowM  = (float*)alloc((size_t)Bb * Ss * 4);
  float* rowIS = (float*)alloc((size_t)Bb * Ss * 4);
  float* colM  = (float*)alloc((size_t)Bb * Ss * 4);
  float* colIS = (float*)alloc((size_t)Bb * Ss * 4);
  float* invLenS = (float*)alloc(Bb * 4);
  float* invLenT = (float*)alloc(Bb * 4);
  float* wsAcc = (float*)alloc(256);
  float* pcM = (float*)alloc((size_t)Bb * 32 * Ss * 4);          // 4 MB
  float* pcS = (float*)alloc((size_t)Bb * 32 * Ss * 4);          // 4 MB

  k_mask<<<Bb, 256, 0, stream>>>(isrc, itgt, extS, extT, invLenS, invLenT, wsAcc);
  k_cvt<<<4096, 256, 0, stream>>>(hsrc, htgt, srcB, tgtB);
  k_gemm<<<dim3(64, Bb), 256, 0, stream>>>(srcB, tgtB, scores);
  k_stats<<<dim3(32, Bb), 256, 0, stream>>>(scores, extS, extT, rowM, rowIS, pcM, pcS);
  k_merge<<<128, 256, 0, stream>>>(pcM, pcS, colM, colIS);
  k_wsum<<<2048, 256, 0, stream>>>(scores, guide, rowM, rowIS, colM, colIS,
                                   extS, extT, invLenS, invLenT, wsAcc);
  k_final<<<1, 1, 0, stream>>>(wsAcc, out);
}